// Round 14
// baseline (9890.112 us; speedup 1.0000x reference)
//
#include <hip/hip_runtime.h>
#include <stdint.h>

#define NB 64
#define NS 1024
#define ND 1024
#define NG 4096
#define CHUNK 128
#define NCHUNK 8
#define RING 32

typedef __attribute__((ext_vector_type(4))) float f32x4;
typedef __attribute__((ext_vector_type(8))) short bf16x8;

__device__ __forceinline__ float bf2f(uint16_t u) {
  return __uint_as_float(((uint32_t)u) << 16);
}
__device__ __forceinline__ uint16_t f2bf(float f) {
  uint32_t x = __float_as_uint(f);
  return (uint16_t)((x + 0x7fffu + ((x >> 16) & 1u)) >> 16);
}
__device__ __forceinline__ float sigmoidf_(float x) {
  return 1.f / (1.f + __expf(-x));
}
__device__ __forceinline__ float tanhf_(float x) {
  return 1.f - 2.f / (__expf(x + x) + 1.f);
}
__device__ __forceinline__ void gload_lds16(const void* g, void* l) {
  __builtin_amdgcn_global_load_lds(
      (const __attribute__((address_space(1))) uint32_t*)g,
      (__attribute__((address_space(3))) uint32_t*)l, 16, 0, 0);
}
// SC0-only (bypass L1, serve from L2): producer agent-stores are same-XCD by
// the claim mapping, so the local L2 is coherent with them.
__device__ __forceinline__ void gload_lds16_l2(const void* g, void* l) {
  __builtin_amdgcn_global_load_lds(
      (const __attribute__((address_space(1))) uint32_t*)g,
      (__attribute__((address_space(3))) uint32_t*)l, 16, 0, 1);
}

// ---------------- convert fp32 -> bf16 ----------------
__global__ void k_cvt(const float* __restrict__ src, uint16_t* __restrict__ dst, int n4) {
  int stride = gridDim.x * blockDim.x;
  for (int i = blockIdx.x * blockDim.x + threadIdx.x; i < n4; i += stride) {
    float4 v = ((const float4*)src)[i];
    ushort4 o;
    o.x = f2bf(v.x); o.y = f2bf(v.y); o.z = f2bf(v.z); o.w = f2bf(v.w);
    ((ushort4*)dst)[i] = o;
  }
}

// all 8 weight matrices in one launch (saves 7 launch overheads)
__global__ void k_cvt8(const float* w0, const float* w1, const float* w2, const float* w3,
                       const float* w4, const float* w5, const float* w6, const float* w7,
                       uint16_t* wx, uint16_t* wh) {
  int which = blockIdx.x >> 8;
  const float* src;
  uint16_t* dst;
  if      (which == 0) { src = w0; dst = wx; }
  else if (which == 1) { src = w1; dst = wx + 1048576; }
  else if (which == 2) { src = w2; dst = wx + 2097152; }
  else if (which == 3) { src = w3; dst = wx + 3145728; }
  else if (which == 4) { src = w4; dst = wh; }
  else if (which == 5) { src = w5; dst = wh + 1048576; }
  else if (which == 6) { src = w6; dst = wh + 2097152; }
  else                 { src = w7; dst = wh + 3145728; }
  for (int i = (blockIdx.x & 255) * 256 + threadIdx.x; i < 262144; i += 65536) {
    float4 v = ((const float4*)src)[i];
    ushort4 o;
    o.x = f2bf(v.x); o.y = f2bf(v.y); o.z = f2bf(v.z); o.w = f2bf(v.w);
    ((ushort4*)dst)[i] = o;
  }
}

// ---------------- GEMM tile: [128 steps x 1024] x [1024 x 128] -> XP ----------------
__device__ __forceinline__ void gemm_tile(const uint16_t* __restrict__ A0,
                                          const uint16_t* __restrict__ Wx,
                                          uint16_t* __restrict__ XP,
                                          int b, int nb, int tid, char* lmem) {
  uint16_t* lAx = (uint16_t*)lmem;
  uint16_t* lBx = (uint16_t*)(lmem + 8192);
  const uint16_t* B0 = Wx + (size_t)(nb * 128) * ND;
  const int lane = tid & 63, wv = tid >> 6;
  const int m_off = (wv >> 1) << 6, n_off = (wv & 1) << 6;

  f32x4 acc[4][4] = {};
  for (int kb = 0; kb < ND / 32; ++kb) {
    const int k0 = kb * 32;
#pragma unroll
    for (int j = 0; j < 2; ++j) {
      int cid = j * 256 + tid;
      int row = cid >> 2, cc = cid & 3;
      int cs = cc ^ (row & 3);
      gload_lds16(A0 + (size_t)row * ND + k0 + cs * 8, (char*)lAx + cid * 16);
      gload_lds16(B0 + (size_t)row * ND + k0 + cs * 8, (char*)lBx + cid * 16);
    }
    __syncthreads();
    bf16x8 af[4], bfr[4];
#pragma unroll
    for (int i = 0; i < 4; ++i) {
      int row = m_off + i * 16 + (lane & 15);
      int ch = (lane >> 4) ^ (row & 3);
      af[i] = *(const bf16x8*)((const char*)lAx + row * 64 + ch * 16);
      int rowb = n_off + i * 16 + (lane & 15);
      int chb = (lane >> 4) ^ (rowb & 3);
      bfr[i] = *(const bf16x8*)((const char*)lBx + rowb * 64 + chb * 16);
    }
#pragma unroll
    for (int i = 0; i < 4; ++i)
#pragma unroll
      for (int j2 = 0; j2 < 4; ++j2)
        acc[i][j2] = __builtin_amdgcn_mfma_f32_16x16x32_bf16(af[i], bfr[j2], acc[i][j2], 0, 0, 0);
    __syncthreads();
  }
#pragma unroll
  for (int i = 0; i < 4; ++i)
#pragma unroll
    for (int j2 = 0; j2 < 4; ++j2)
#pragma unroll
      for (int r = 0; r < 4; ++r) {
        int m = m_off + i * 16 + ((lane >> 4) << 2) + r;
        int n = nb * 128 + n_off + j2 * 16 + (lane & 15);
        XP[((size_t)(m * NB + b)) * NG + n] = f2bf(acc[i][j2][r]);
      }
}

// ---------------- fused dispatch (XCD-claimed roles) ----------------
// 96KB dynamic LDS -> 1 WG/CU -> exactly 32 WGs per XCD. Each WG claims a slot
// on its hardware XCD: XCD 0..3 -> LSTM group g_b=xcd, d-slice g_d=slot (all
// sync traffic same-XCD -> L2 latency); XCD 4..7 -> GEMM with XCD-local
// b-partition (16 batches/XCD: A-tiles resident in that XCD's L2).
// Correctness never depends on the mapping (agent-scope ops + same-XCD L2
// coherence for h; XP crosses dispatches -> flushed at kernel boundary).
__global__ __launch_bounds__(512, 2) void k_fused(
    const uint16_t* __restrict__ embb,   // [64][1024][1024] bf16
    const uint16_t* __restrict__ Wx,
    const uint16_t* __restrict__ Wh,
    uint16_t* __restrict__ xpA, uint16_t* __restrict__ xpB,
    const float* __restrict__ b_i, const float* __restrict__ b_f,
    const float* __restrict__ b_g, const float* __restrict__ b_o,
    uint16_t* __restrict__ hring,        // [RING][NB][ND] bf16 ring (t mod 32)
    float* __restrict__ cbuf,
    uint32_t* __restrict__ flags,        // [NS][4][32] slots, 16B stride
    uint32_t* __restrict__ claim,        // [NCHUNK+1][8] per-XCD slot counters
    float* __restrict__ out, int chunk) {
  extern __shared__ char smem[];
  const int bid = blockIdx.x;
  const int tid = threadIdx.x;

  int xcc = 0, slot = 0;
  if (chunk >= 0) {
    __shared__ int s_role;
    if (tid == 0) {
      int x = (int)(__builtin_amdgcn_s_getreg((31 << 11) | 20)) & 7;   // HW_REG_XCC_ID
      int s = (int)atomicAdd(&claim[(chunk + 1) * 8 + x], 1u);
      s_role = (x << 8) | s;
    }
    __syncthreads();
    int rv = s_role;
    xcc = rv >> 8; slot = rv & 255;
  }

  if (chunk < 0 || xcc >= 4) {
    // ---------------- GEMM role: x_proj for chunk+1 ----------------
    const int gc = (chunk < 0) ? 0 : chunk + 1;
    if (gc >= NCHUNK) return;
    uint16_t* XP = (gc & 1) ? xpB : xpA;
    const int t256 = tid & 255;
    char* lmem = smem + ((tid >> 8) << 14);
    const int t0g = gc * CHUNK;
    if (chunk < 0) {
      // prologue: 512 workers, linear 2b x 2nb blocks (R12-proven)
      int w = bid * 2 + (tid >> 8);
      int wb = w & 31, wn = w >> 5;
#pragma unroll
      for (int nbi = 0; nbi < 2; ++nbi)
#pragma unroll
        for (int bi = 0; bi < 2; ++bi) {
          int b = wb * 2 + bi, nb = wn * 2 + nbi;
          gemm_tile(embb + ((size_t)b * NS + t0g) * ND, Wx, XP, b, nb, t256, lmem);
        }
    } else {
      // steady: XCD-local b partition. XCD x' owns b in [x'*16, x'*16+16):
      // 4 MB of A resident per XCD L2; 4 concurrent nb slices (1 MB Wx live).
      int xp2 = xcc - 4;                     // 0..3
      int u = slot * 2 + (tid >> 8);         // 0..63 within XCD
      int b = xp2 * 16 + (u & 15);
      int nb0 = u >> 4;                      // 0..3
      const uint16_t* A0 = embb + ((size_t)b * NS + t0g) * ND;
#pragma unroll
      for (int k2 = 0; k2 < 8; ++k2)
        gemm_tile(A0, Wx, XP, b, nb0 + 4 * k2, t256, lmem);
    }
    return;
  }

  // ---------------- LSTM role (R12 skeleton; g_b/g_d from claim) ----------------
  uint16_t* lH = (uint16_t*)smem;                 // 32 KB: 16 rows x 2048 B
  int* lds_sync = (int*)(smem + 32768);
  const int t0 = chunk * CHUNK;
  const uint16_t* XP = (chunk & 1) ? xpB : xpA;

  const int lane = tid & 63, wv = tid >> 6;
  const int g_b = xcc;                         // batch group, all WGs same-XCD
  const int g_d = slot;                        // 0..31

  const int q = lane >> 4, nl = lane & 15;
  const int g = nl & 3;                        // gate id (0=i,1=f,2=g,3=o)
  const int d_loc = wv * 4 + (nl >> 2);        // 0..31
  const int dg = g_d * 32 + d_loc;             // global d
  const int bg0 = g_b * 16 + q * 4;            // batch base for r=0..3

  const uint16_t* wrow = Wh + ((size_t)g * ND + dg) * ND;
  bf16x8 wfr[32];
#pragma unroll
  for (int kk = 0; kk < 32; ++kk)
    wfr[kk] = *(const bf16x8*)(wrow + kk * 32 + q * 8);

  const float* bptr = (g == 0) ? b_i : (g == 1) ? b_f : (g == 2) ? b_g : b_o;
  const float Bv = bptr[dg];

  float c0, c1, c2, c3;
  if (t0 == 0) {
    c0 = c1 = c2 = c3 = 0.f;
  } else {
    c0 = cbuf[(size_t)(bg0 + 0) * ND + dg];
    c1 = cbuf[(size_t)(bg0 + 1) * ND + dg];
    c2 = cbuf[(size_t)(bg0 + 2) * ND + dg];
    c3 = cbuf[(size_t)(bg0 + 3) * ND + dg];
  }

  if (tid == 0)
    __hip_atomic_store(lds_sync, t0, __ATOMIC_RELAXED, __HIP_MEMORY_SCOPE_WORKGROUP);
  __syncthreads();

  // preload XP for t0
  const uint16_t* xp0 = XP + ((size_t)bg0) * NG + ((size_t)g << 10) + dg;
  uint16_t xc0 = xp0[0], xc1 = xp0[NG], xc2 = xp0[2 * (size_t)NG], xc3 = xp0[3 * (size_t)NG];

#pragma unroll 1
  for (int t = t0; t < t0 + CHUNK; ++t) {
    f32x4 a0 = {0,0,0,0}, a1 = {0,0,0,0}, a2 = {0,0,0,0}, a3 = {0,0,0,0};
    if (t > 0) {
      if (wv == 0) {
        // gather all 32 producer flags in one 32-lane load (slots 16B-strided)
        const uint32_t* fl = flags + ((((size_t)(t - 1) * 4 + g_b) << 5) + (lane & 31)) * 4;
        uint32_t v;
        do {
          v = __hip_atomic_load(fl, __ATOMIC_RELAXED, __HIP_MEMORY_SCOPE_AGENT);
        } while (__any(v == 0));
        if (lane == 0)
          __hip_atomic_store(lds_sync, t, __ATOMIC_RELAXED, __HIP_MEMORY_SCOPE_WORKGROUP);
      } else {
        while (__hip_atomic_load(lds_sync, __ATOMIC_RELAXED, __HIP_MEMORY_SCOPE_WORKGROUP) < t) {}
      }
      // stage h(t-1) from ring slot: 32 KB, L1-bypass gload_lds (L2-coherent same-XCD)
      const uint16_t* hbase = hring + (size_t)((t - 1) & (RING - 1)) * NB * ND;
#pragma unroll
      for (int j = 0; j < 4; ++j) {
        int ch = wv * 64 + j * 512 + lane;       // 0..2047
        int row = ch >> 7, c = ch & 127;
        const uint16_t* src = hbase + (size_t)(g_b * 16 + row) * ND + ((c ^ (row & 7)) << 3);
        gload_lds16_l2(src, (char*)lH + ch * 16);
      }
      __syncthreads();
    }

    // prefetch next step's XP into regs (covered by MFMA+VALU below)
    int tn = t + 1 < t0 + CHUNK ? t + 1 : t;
    const uint16_t* xpn = XP + (((size_t)(tn - t0) * NB) + bg0) * NG + ((size_t)g << 10) + dg;
    uint16_t xn0 = xpn[0], xn1 = xpn[NG], xn2 = xpn[2 * (size_t)NG], xn3 = xpn[3 * (size_t)NG];

    if (t > 0) {
#pragma unroll
      for (int kk = 0; kk < 32; ++kk) {
        int cs = (kk * 4 + q) ^ (nl & 7);
        bf16x8 af = *(const bf16x8*)((const char*)lH + nl * 2048 + cs * 16);
        if ((kk & 3) == 0)      a0 = __builtin_amdgcn_mfma_f32_16x16x32_bf16(af, wfr[kk], a0, 0, 0, 0);
        else if ((kk & 3) == 1) a1 = __builtin_amdgcn_mfma_f32_16x16x32_bf16(af, wfr[kk], a1, 0, 0, 0);
        else if ((kk & 3) == 2) a2 = __builtin_amdgcn_mfma_f32_16x16x32_bf16(af, wfr[kk], a2, 0, 0, 0);
        else                    a3 = __builtin_amdgcn_mfma_f32_16x16x32_bf16(af, wfr[kk], a3, 0, 0, 0);
      }
    }

    float xr[4] = { bf2f(xc0), bf2f(xc1), bf2f(xc2), bf2f(xc3) };
    float cc[4] = { c0, c1, c2, c3 };
    float hval = 0.f;
#pragma unroll
    for (int r = 0; r < 4; ++r) {
      float v = a0[r] + a1[r] + a2[r] + a3[r] + xr[r] + Bv;
      float act = (g == 2) ? tanhf_(v) : sigmoidf_(v);
      float s1 = __shfl_xor(act, 1);
      float pe = (g & 1) ? s1 : act;
      float po = (g & 1) ? act : s1;
      float qe = __shfl_xor(pe, 2);
      float qo = __shfl_xor(po, 2);
      float gi = (g & 2) ? qe : pe;
      float gf = (g & 2) ? qo : po;
      float gg2 = (g & 2) ? pe : qe;
      float go = (g & 2) ? po : qo;
      float cn = __builtin_fmaf(gf, cc[r], gi * gg2);
      cc[r] = cn;
      float h = go * tanhf_(cn);
      if (r == g) hval = h;
    }
    c0 = cc[0]; c1 = cc[1]; c2 = cc[2]; c3 = cc[3];

    // per-wave shuffle-pack: 4 lanes (same q, d_off 0..3) -> u64 in nl<4
    {
      int hv = (int)f2bf(hval);
      int p = __shfl_xor(hv, 4);
      uint32_t v32 = ((nl >> 2) & 1) ? ((uint32_t)p | ((uint32_t)hv << 16))
                                     : ((uint32_t)hv | ((uint32_t)p << 16));
      uint32_t hi = (uint32_t)__shfl_xor((int)v32, 8);
      if (nl < 4) {
        uint64_t val = (uint64_t)v32 | ((uint64_t)hi << 32);
        uint16_t* dst = hring + (size_t)(t & (RING - 1)) * NB * ND
                        + (size_t)(g_b * 16 + q * 4 + nl) * ND + g_d * 32 + wv * 4;
        __hip_atomic_store((uint64_t*)dst, val, __ATOMIC_RELAXED, __HIP_MEMORY_SCOPE_AGENT);
      }
    }
    if (t == NS - 1) out[(size_t)(bg0 + g) * ND + dg] = hval;

    __syncthreads();   // drains all waves' h stores; guards lH reuse
    if (tid == 0)
      __hip_atomic_store(flags + ((((size_t)t * 4 + g_b) << 5) + g_d) * 4, 1u,
                         __ATOMIC_RELAXED, __HIP_MEMORY_SCOPE_AGENT);

    xc0 = xn0; xc1 = xn1; xc2 = xn2; xc3 = xn3;
  }

  float cstore = (g == 0) ? c0 : (g == 1) ? c1 : (g == 2) ? c2 : c3;
  cbuf[(size_t)(bg0 + g) * ND + dg] = cstore;
}

// ---------------- launch ----------------
extern "C" void kernel_launch(void* const* d_in, const int* in_sizes, int n_in,
                              void* d_out, int out_size, void* d_ws, size_t ws_size,
                              hipStream_t stream) {
  const float* emb = (const float*)d_in[0];
  const float* W_ii = (const float*)d_in[1];
  const float* b_ii = (const float*)d_in[2];
  const float* W_if = (const float*)d_in[3];
  const float* b_if = (const float*)d_in[4];
  const float* W_ig = (const float*)d_in[5];
  const float* b_ig = (const float*)d_in[6];
  const float* W_io = (const float*)d_in[7];
  const float* b_io = (const float*)d_in[8];
  const float* W_hi = (const float*)d_in[9];
  const float* W_hf = (const float*)d_in[10];
  const float* W_hg = (const float*)d_in[11];
  const float* W_ho = (const float*)d_in[12];

  char* ws = (char*)d_ws;
  uint16_t* embb  = (uint16_t*)ws;                       // 134217728 B [B][S][D] bf16
  uint16_t* wx    = (uint16_t*)(ws + 134217728);         // 8388608 B
  uint16_t* wh    = (uint16_t*)(ws + 142606336);         // 8388608 B
  uint16_t* xpA   = (uint16_t*)(ws + 150994944);         // 67108864 B
  uint16_t* xpB   = (uint16_t*)(ws + 218103808);         // 67108864 B
  uint16_t* hring = (uint16_t*)(ws + 285212672);         // 4194304 B [RING][NB][ND]
  float*    cbuf  = (float*)(ws + 289406976);            // 262144 B
  uint32_t* flags = (uint32_t*)(ws + 289669120);         // 2097152 B [NS][4][32] x16B
  uint32_t* claim = (uint32_t*)(ws + 291766272);         // 288 B [9][8]

  hipMemsetAsync(flags, 0, 2097152 + 512, stream);

  k_cvt<<<2048, 256, 0, stream>>>(emb, embb, 64 * 1024 * 1024 / 4);
  k_cvt8<<<2048, 256, 0, stream>>>(W_ii, W_if, W_ig, W_io, W_hi, W_hf, W_hg, W_ho, wx, wh);

  const int SHM = 98304;   // 96 KB -> 1 WG/CU (forces the 32-WG/XCD bijection)
  hipFuncSetAttribute((const void*)k_fused, hipFuncAttributeMaxDynamicSharedMemorySize, SHM);

  // prologue: all 256 WGs compute x_proj for chunk 0
  k_fused<<<256, 512, SHM, stream>>>(embb, wx, wh, xpA, xpB, b_ii, b_if, b_ig, b_io,
                                     hring, cbuf, flags, claim, (float*)d_out, -1);
  for (int chk = 0; chk < NCHUNK; ++chk)
    k_fused<<<256, 512, SHM, stream>>>(embb, wx, wh, xpA, xpB, b_ii, b_if, b_ig, b_io,
                                       hring, cbuf, flags, claim, (float*)d_out, chk);
}

// Round 15
// 3596.981 us; speedup vs baseline: 2.7496x; 2.7496x over previous
//
#include <hip/hip_runtime.h>
#include <stdint.h>

#define NB 64
#define NS 1024
#define ND 1024
#define NG 4096
#define CHUNK 128
#define NCHUNK 8
#define RING 32

typedef __attribute__((ext_vector_type(4))) float f32x4;
typedef __attribute__((ext_vector_type(8))) short bf16x8;

__device__ __forceinline__ float bf2f(uint16_t u) {
  return __uint_as_float(((uint32_t)u) << 16);
}
__device__ __forceinline__ uint16_t f2bf(float f) {
  uint32_t x = __float_as_uint(f);
  return (uint16_t)((x + 0x7fffu + ((x >> 16) & 1u)) >> 16);
}
__device__ __forceinline__ float sigmoidf_(float x) {
  return 1.f / (1.f + __expf(-x));
}
__device__ __forceinline__ float tanhf_(float x) {
  return 1.f - 2.f / (__expf(x + x) + 1.f);
}
__device__ __forceinline__ void gload_lds16(const void* g, void* l) {
  __builtin_amdgcn_global_load_lds(
      (const __attribute__((address_space(1))) uint32_t*)g,
      (__attribute__((address_space(3))) uint32_t*)l, 16, 0, 0);
}
// L1+L2-bypassing variant (cpol SC0|SC1): reads served from L3, where the
// producers' agent-scope stores are visible before their flag.
__device__ __forceinline__ void gload_lds16_nc(const void* g, void* l) {
  __builtin_amdgcn_global_load_lds(
      (const __attribute__((address_space(1))) uint32_t*)g,
      (__attribute__((address_space(3))) uint32_t*)l, 16, 0, 17);
}

// ---------------- convert fp32 -> bf16 (emb) ----------------
__global__ void k_cvt(const float* __restrict__ src, uint16_t* __restrict__ dst, int n4) {
  int stride = gridDim.x * blockDim.x;
  for (int i = blockIdx.x * blockDim.x + threadIdx.x; i < n4; i += stride) {
    float4 v = ((const float4*)src)[i];
    ushort4 o;
    o.x = f2bf(v.x); o.y = f2bf(v.y); o.z = f2bf(v.z); o.w = f2bf(v.w);
    ((ushort4*)dst)[i] = o;
  }
}

// all 8 weight matrices in one launch (saves 7 launch overheads; R14-verified)
__global__ void k_cvt8(const float* w0, const float* w1, const float* w2, const float* w3,
                       const float* w4, const float* w5, const float* w6, const float* w7,
                       uint16_t* wx, uint16_t* wh) {
  int which = blockIdx.x >> 8;
  const float* src;
  uint16_t* dst;
  if      (which == 0) { src = w0; dst = wx; }
  else if (which == 1) { src = w1; dst = wx + 1048576; }
  else if (which == 2) { src = w2; dst = wx + 2097152; }
  else if (which == 3) { src = w3; dst = wx + 3145728; }
  else if (which == 4) { src = w4; dst = wh; }
  else if (which == 5) { src = w5; dst = wh + 1048576; }
  else if (which == 6) { src = w6; dst = wh + 2097152; }
  else                 { src = w7; dst = wh + 3145728; }
  for (int i = (blockIdx.x & 255) * 256 + threadIdx.x; i < 262144; i += 65536) {
    float4 v = ((const float4*)src)[i];
    ushort4 o;
    o.x = f2bf(v.x); o.y = f2bf(v.y); o.z = f2bf(v.z); o.w = f2bf(v.w);
    ((ushort4*)dst)[i] = o;
  }
}

// ---------------- GEMM tile: [128 steps x 1024] x [1024 x 128] -> XP ----------------
__device__ __forceinline__ void gemm_tile(const uint16_t* __restrict__ A0,
                                          const uint16_t* __restrict__ Wx,
                                          uint16_t* __restrict__ XP,
                                          int b, int nb, int tid, char* lmem) {
  uint16_t* lAx = (uint16_t*)lmem;
  uint16_t* lBx = (uint16_t*)(lmem + 8192);
  const uint16_t* B0 = Wx + (size_t)(nb * 128) * ND;
  const int lane = tid & 63, wv = tid >> 6;
  const int m_off = (wv >> 1) << 6, n_off = (wv & 1) << 6;

  f32x4 acc[4][4] = {};
  for (int kb = 0; kb < ND / 32; ++kb) {
    const int k0 = kb * 32;
#pragma unroll
    for (int j = 0; j < 2; ++j) {
      int cid = j * 256 + tid;
      int row = cid >> 2, cc = cid & 3;
      int cs = cc ^ (row & 3);
      gload_lds16(A0 + (size_t)row * ND + k0 + cs * 8, (char*)lAx + cid * 16);
      gload_lds16(B0 + (size_t)row * ND + k0 + cs * 8, (char*)lBx + cid * 16);
    }
    __syncthreads();
    bf16x8 af[4], bfr[4];
#pragma unroll
    for (int i = 0; i < 4; ++i) {
      int row = m_off + i * 16 + (lane & 15);
      int ch = (lane >> 4) ^ (row & 3);
      af[i] = *(const bf16x8*)((const char*)lAx + row * 64 + ch * 16);
      int rowb = n_off + i * 16 + (lane & 15);
      int chb = (lane >> 4) ^ (rowb & 3);
      bfr[i] = *(const bf16x8*)((const char*)lBx + rowb * 64 + chb * 16);
    }
#pragma unroll
    for (int i = 0; i < 4; ++i)
#pragma unroll
      for (int j2 = 0; j2 < 4; ++j2)
        acc[i][j2] = __builtin_amdgcn_mfma_f32_16x16x32_bf16(af[i], bfr[j2], acc[i][j2], 0, 0, 0);
    __syncthreads();
  }
#pragma unroll
  for (int i = 0; i < 4; ++i)
#pragma unroll
    for (int j2 = 0; j2 < 4; ++j2)
#pragma unroll
      for (int r = 0; r < 4; ++r) {
        int m = m_off + i * 16 + ((lane >> 4) << 2) + r;
        int n = nb * 128 + n_off + j2 * 16 + (lane & 15);
        XP[((size_t)(m * NB + b)) * NG + n] = f2bf(acc[i][j2][r]);
      }
}

// ---------------- fused dispatch (R12-verified skeleton) ----------------
// bids 0..127: LSTM (g_b 0..3 x g_d 0..31). bids 128..255: GEMM for chunk+1.
// 96KB dynamic LDS -> 1 WG/CU. h lives in a 32-step ring; consumers read it
// with L1/L2-bypass gload_lds (producers' agent stores are L3-visible by flag).
__global__ __launch_bounds__(512, 2) void k_fused(
    const uint16_t* __restrict__ embb,   // [64][1024][1024] bf16
    const uint16_t* __restrict__ Wx,
    const uint16_t* __restrict__ Wh,
    uint16_t* __restrict__ xpA, uint16_t* __restrict__ xpB,
    const float* __restrict__ b_i, const float* __restrict__ b_f,
    const float* __restrict__ b_g, const float* __restrict__ b_o,
    uint16_t* __restrict__ hring,        // [RING][NB][ND] bf16 ring (t mod 32)
    float* __restrict__ cbuf,
    uint32_t* __restrict__ flags,        // [NS][4][32] slots, 16B stride
    float* __restrict__ out, int chunk) {
  extern __shared__ char smem[];
  const int bid = blockIdx.x;
  const int tid = threadIdx.x;

  if (chunk < 0 || bid >= 128) {
    // ---------------- GEMM role: x_proj for chunk+1 ----------------
    const int gc = (chunk < 0) ? 0 : chunk + 1;
    if (gc >= NCHUNK) return;
    uint16_t* XP = (gc & 1) ? xpB : xpA;
    const int nw = (chunk < 0) ? 512 : 256;
    const int widx = ((chunk < 0) ? bid : bid - 128) * 2 + (tid >> 8);
    const int t256 = tid & 255;
    char* lmem = smem + ((tid >> 8) << 14);
    const int t0g = gc * CHUNK;
    for (int job = widx; job < 64 * 32; job += nw) {
      int b = job & 63, nb = job >> 6;
      gemm_tile(embb + ((size_t)b * NS + t0g) * ND, Wx, XP, b, nb, t256, lmem);
    }
    return;
  }

  // ---------------- LSTM role ----------------
  uint16_t* lH = (uint16_t*)smem;                 // 32 KB: 16 rows x 2048 B
  int* lds_sync = (int*)(smem + 32768);
  const int t0 = chunk * CHUNK;
  const uint16_t* XP = (chunk & 1) ? xpB : xpA;

  const int lane = tid & 63, wv = tid >> 6;
  const int xcd = bid & 7;
  const int g_b = xcd >> 1;
  const int g_d = (xcd & 1) + ((bid >> 3) << 1);  // 0..31

  const int q = lane >> 4, nl = lane & 15;
  const int g = nl & 3;                        // gate id (0=i,1=f,2=g,3=o)
  const int d_loc = wv * 4 + (nl >> 2);        // 0..31
  const int dg = g_d * 32 + d_loc;             // global d
  const int bg0 = g_b * 16 + q * 4;            // batch base for r=0..3

  const uint16_t* wrow = Wh + ((size_t)g * ND + dg) * ND;
  bf16x8 wfr[32];
#pragma unroll
  for (int kk = 0; kk < 32; ++kk)
    wfr[kk] = *(const bf16x8*)(wrow + kk * 32 + q * 8);

  const float* bptr = (g == 0) ? b_i : (g == 1) ? b_f : (g == 2) ? b_g : b_o;
  const float Bv = bptr[dg];

  float c0, c1, c2, c3;
  if (t0 == 0) {
    c0 = c1 = c2 = c3 = 0.f;
  } else {
    c0 = cbuf[(size_t)(bg0 + 0) * ND + dg];
    c1 = cbuf[(size_t)(bg0 + 1) * ND + dg];
    c2 = cbuf[(size_t)(bg0 + 2) * ND + dg];
    c3 = cbuf[(size_t)(bg0 + 3) * ND + dg];
  }

  if (tid == 0)
    __hip_atomic_store(lds_sync, t0, __ATOMIC_RELAXED, __HIP_MEMORY_SCOPE_WORKGROUP);
  __syncthreads();

  // preload XP for t0
  const uint16_t* xp0 = XP + ((size_t)bg0) * NG + ((size_t)g << 10) + dg;
  uint16_t xc0 = xp0[0], xc1 = xp0[NG], xc2 = xp0[2 * (size_t)NG], xc3 = xp0[3 * (size_t)NG];

#pragma unroll 1
  for (int t = t0; t < t0 + CHUNK; ++t) {
    f32x4 a0 = {0,0,0,0}, a1 = {0,0,0,0}, a2 = {0,0,0,0}, a3 = {0,0,0,0};
    if (t > 0) {
      if (wv == 0) {
        // gather all 32 producer flags in one 32-lane load (slots 16B-strided)
        const uint32_t* fl = flags + ((((size_t)(t - 1) * 4 + g_b) << 5) + (lane & 31)) * 4;
        uint32_t v;
        do {
          v = __hip_atomic_load(fl, __ATOMIC_RELAXED, __HIP_MEMORY_SCOPE_AGENT);
        } while (__any(v == 0));
        if (lane == 0)
          __hip_atomic_store(lds_sync, t, __ATOMIC_RELAXED, __HIP_MEMORY_SCOPE_WORKGROUP);
      } else {
        while (__hip_atomic_load(lds_sync, __ATOMIC_RELAXED, __HIP_MEMORY_SCOPE_WORKGROUP) < t) {}
      }
      // stage h(t-1) from ring slot (t-1)&31: 32 KB, L1/L2-bypass gload_lds
      const uint16_t* hbase = hring + (size_t)((t - 1) & (RING - 1)) * NB * ND;
#pragma unroll
      for (int j = 0; j < 4; ++j) {
        int ch = wv * 64 + j * 512 + lane;       // 0..2047
        int row = ch >> 7, c = ch & 127;
        const uint16_t* src = hbase + (size_t)(g_b * 16 + row) * ND + ((c ^ (row & 7)) << 3);
        gload_lds16_nc(src, (char*)lH + ch * 16);
      }
      __syncthreads();
    }

    // prefetch next step's XP into regs (covered by MFMA+VALU below)
    int tn = t + 1 < t0 + CHUNK ? t + 1 : t;
    const uint16_t* xpn = XP + (((size_t)(tn - t0) * NB) + bg0) * NG + ((size_t)g << 10) + dg;
    uint16_t xn0 = xpn[0], xn1 = xpn[NG], xn2 = xpn[2 * (size_t)NG], xn3 = xpn[3 * (size_t)NG];

    if (t > 0) {
#pragma unroll
      for (int kk = 0; kk < 32; ++kk) {
        int cs = (kk * 4 + q) ^ (nl & 7);
        bf16x8 af = *(const bf16x8*)((const char*)lH + nl * 2048 + cs * 16);
        if ((kk & 3) == 0)      a0 = __builtin_amdgcn_mfma_f32_16x16x32_bf16(af, wfr[kk], a0, 0, 0, 0);
        else if ((kk & 3) == 1) a1 = __builtin_amdgcn_mfma_f32_16x16x32_bf16(af, wfr[kk], a1, 0, 0, 0);
        else if ((kk & 3) == 2) a2 = __builtin_amdgcn_mfma_f32_16x16x32_bf16(af, wfr[kk], a2, 0, 0, 0);
        else                    a3 = __builtin_amdgcn_mfma_f32_16x16x32_bf16(af, wfr[kk], a3, 0, 0, 0);
      }
    }

    float xr[4] = { bf2f(xc0), bf2f(xc1), bf2f(xc2), bf2f(xc3) };
    float cc[4] = { c0, c1, c2, c3 };
    float hval = 0.f;
#pragma unroll
    for (int r = 0; r < 4; ++r) {
      float v = a0[r] + a1[r] + a2[r] + a3[r] + xr[r] + Bv;
      float act = (g == 2) ? tanhf_(v) : sigmoidf_(v);
      float s1 = __shfl_xor(act, 1);
      float pe = (g & 1) ? s1 : act;
      float po = (g & 1) ? act : s1;
      float qe = __shfl_xor(pe, 2);
      float qo = __shfl_xor(po, 2);
      float gi = (g & 2) ? qe : pe;
      float gf = (g & 2) ? qo : po;
      float gg2 = (g & 2) ? pe : qe;
      float go = (g & 2) ? po : qo;
      float cn = __builtin_fmaf(gf, cc[r], gi * gg2);
      cc[r] = cn;
      float h = go * tanhf_(cn);
      if (r == g) hval = h;
    }
    c0 = cc[0]; c1 = cc[1]; c2 = cc[2]; c3 = cc[3];

    // per-wave shuffle-pack: 4 lanes (same q, d_off 0..3) -> u64 in nl<4
    {
      int hv = (int)f2bf(hval);
      int p = __shfl_xor(hv, 4);
      uint32_t v32 = ((nl >> 2) & 1) ? ((uint32_t)p | ((uint32_t)hv << 16))
                                     : ((uint32_t)hv | ((uint32_t)p << 16));
      uint32_t hi = (uint32_t)__shfl_xor((int)v32, 8);
      if (nl < 4) {
        uint64_t val = (uint64_t)v32 | ((uint64_t)hi << 32);
        uint16_t* dst = hring + (size_t)(t & (RING - 1)) * NB * ND
                        + (size_t)(g_b * 16 + q * 4 + nl) * ND + g_d * 32 + wv * 4;
        __hip_atomic_store((uint64_t*)dst, val, __ATOMIC_RELAXED, __HIP_MEMORY_SCOPE_AGENT);
      }
    }
    if (t == NS - 1) out[(size_t)(bg0 + g) * ND + dg] = hval;

    __syncthreads();   // drains all waves' h stores; guards lH reuse
    if (tid == 0)
      __hip_atomic_store(flags + ((((size_t)t * 4 + g_b) << 5) + g_d) * 4, 1u,
                         __ATOMIC_RELAXED, __HIP_MEMORY_SCOPE_AGENT);

    xc0 = xn0; xc1 = xn1; xc2 = xn2; xc3 = xn3;
  }

  float cstore = (g == 0) ? c0 : (g == 1) ? c1 : (g == 2) ? c2 : c3;
  cbuf[(size_t)(bg0 + g) * ND + dg] = cstore;
}

// ---------------- launch ----------------
extern "C" void kernel_launch(void* const* d_in, const int* in_sizes, int n_in,
                              void* d_out, int out_size, void* d_ws, size_t ws_size,
                              hipStream_t stream) {
  const float* emb = (const float*)d_in[0];
  const float* W_ii = (const float*)d_in[1];
  const float* b_ii = (const float*)d_in[2];
  const float* W_if = (const float*)d_in[3];
  const float* b_if = (const float*)d_in[4];
  const float* W_ig = (const float*)d_in[5];
  const float* b_ig = (const float*)d_in[6];
  const float* W_io = (const float*)d_in[7];
  const float* b_io = (const float*)d_in[8];
  const float* W_hi = (const float*)d_in[9];
  const float* W_hf = (const float*)d_in[10];
  const float* W_hg = (const float*)d_in[11];
  const float* W_ho = (const float*)d_in[12];

  char* ws = (char*)d_ws;
  uint16_t* embb  = (uint16_t*)ws;                       // 134217728 B [B][S][D] bf16
  uint16_t* wx    = (uint16_t*)(ws + 134217728);         // 8388608 B
  uint16_t* wh    = (uint16_t*)(ws + 142606336);         // 8388608 B
  uint16_t* xpA   = (uint16_t*)(ws + 150994944);         // 67108864 B
  uint16_t* xpB   = (uint16_t*)(ws + 218103808);         // 67108864 B
  uint16_t* hring = (uint16_t*)(ws + 285212672);         // 4194304 B [RING][NB][ND]
  float*    cbuf  = (float*)(ws + 289406976);            // 262144 B
  uint32_t* flags = (uint32_t*)(ws + 289669120);         // 2097152 B [NS][4][32] x16B

  hipMemsetAsync(flags, 0, 2097152, stream);

  k_cvt<<<2048, 256, 0, stream>>>(emb, embb, 64 * 1024 * 1024 / 4);
  k_cvt8<<<2048, 256, 0, stream>>>(W_ii, W_if, W_ig, W_io, W_hi, W_hf, W_hg, W_ho, wx, wh);

  const int SHM = 98304;   // 96 KB -> 1 WG/CU (R9/R12-verified)
  hipFuncSetAttribute((const void*)k_fused, hipFuncAttributeMaxDynamicSharedMemorySize, SHM);

  // prologue: all 256 WGs compute x_proj for chunk 0
  k_fused<<<256, 512, SHM, stream>>>(embb, wx, wh, xpA, xpB, b_ii, b_if, b_ig, b_io,
                                     hring, cbuf, flags, (float*)d_out, -1);
  for (int chk = 0; chk < NCHUNK; ++chk)
    k_fused<<<256, 512, SHM, stream>>>(embb, wx, wh, xpA, xpB, b_ii, b_if, b_ig, b_io,
                                       hring, cbuf, flags, (float*)d_out, chk);
}

// Round 16
// 3413.248 us; speedup vs baseline: 2.8976x; 1.0538x over previous
//
#include <hip/hip_runtime.h>
#include <stdint.h>

#define NB 64
#define NS 1024
#define ND 1024
#define NG 4096
#define CHUNK 128
#define NCHUNK 8
#define RING 32

typedef __attribute__((ext_vector_type(4))) float f32x4;
typedef __attribute__((ext_vector_type(8))) short bf16x8;

__device__ __forceinline__ float bf2f(uint16_t u) {
  return __uint_as_float(((uint32_t)u) << 16);
}
__device__ __forceinline__ uint16_t f2bf(float f) {
  uint32_t x = __float_as_uint(f);
  return (uint16_t)((x + 0x7fffu + ((x >> 16) & 1u)) >> 16);
}
__device__ __forceinline__ float sigmoidf_(float x) {
  return 1.f / (1.f + __expf(-x));
}
__device__ __forceinline__ float tanhf_(float x) {
  return 1.f - 2.f / (__expf(x + x) + 1.f);
}
__device__ __forceinline__ void gload_lds16(const void* g, void* l) {
  __builtin_amdgcn_global_load_lds(
      (const __attribute__((address_space(1))) uint32_t*)g,
      (__attribute__((address_space(3))) uint32_t*)l, 16, 0, 0);
}
// L1+L2-bypassing variant (cpol SC0|SC1): reads served from L3, where the
// producers' agent-scope stores are visible before their flag.
__device__ __forceinline__ void gload_lds16_nc(const void* g, void* l) {
  __builtin_amdgcn_global_load_lds(
      (const __attribute__((address_space(1))) uint32_t*)g,
      (__attribute__((address_space(3))) uint32_t*)l, 16, 0, 17);
}

// ---------------- convert fp32 -> bf16 (emb) ----------------
__global__ void k_cvt(const float* __restrict__ src, uint16_t* __restrict__ dst, int n4) {
  int stride = gridDim.x * blockDim.x;
  for (int i = blockIdx.x * blockDim.x + threadIdx.x; i < n4; i += stride) {
    float4 v = ((const float4*)src)[i];
    ushort4 o;
    o.x = f2bf(v.x); o.y = f2bf(v.y); o.z = f2bf(v.z); o.w = f2bf(v.w);
    ((ushort4*)dst)[i] = o;
  }
}

// all 8 weight matrices in one launch (saves 7 launch overheads; R14-verified)
__global__ void k_cvt8(const float* w0, const float* w1, const float* w2, const float* w3,
                       const float* w4, const float* w5, const float* w6, const float* w7,
                       uint16_t* wx, uint16_t* wh) {
  int which = blockIdx.x >> 8;
  const float* src;
  uint16_t* dst;
  if      (which == 0) { src = w0; dst = wx; }
  else if (which == 1) { src = w1; dst = wx + 1048576; }
  else if (which == 2) { src = w2; dst = wx + 2097152; }
  else if (which == 3) { src = w3; dst = wx + 3145728; }
  else if (which == 4) { src = w4; dst = wh; }
  else if (which == 5) { src = w5; dst = wh + 1048576; }
  else if (which == 6) { src = w6; dst = wh + 2097152; }
  else                 { src = w7; dst = wh + 3145728; }
  for (int i = (blockIdx.x & 255) * 256 + threadIdx.x; i < 262144; i += 65536) {
    float4 v = ((const float4*)src)[i];
    ushort4 o;
    o.x = f2bf(v.x); o.y = f2bf(v.y); o.z = f2bf(v.z); o.w = f2bf(v.w);
    ((ushort4*)dst)[i] = o;
  }
}

// ---------------- GEMM tile: [128 steps x 1024] x [1024 x 128] -> XP ----------------
__device__ __forceinline__ void gemm_tile(const uint16_t* __restrict__ A0,
                                          const uint16_t* __restrict__ Wx,
                                          uint16_t* __restrict__ XP,
                                          int b, int nb, int tid, char* lmem) {
  uint16_t* lAx = (uint16_t*)lmem;
  uint16_t* lBx = (uint16_t*)(lmem + 8192);
  const uint16_t* B0 = Wx + (size_t)(nb * 128) * ND;
  const int lane = tid & 63, wv = tid >> 6;
  const int m_off = (wv >> 1) << 6, n_off = (wv & 1) << 6;

  f32x4 acc[4][4] = {};
  for (int kb = 0; kb < ND / 32; ++kb) {
    const int k0 = kb * 32;
#pragma unroll
    for (int j = 0; j < 2; ++j) {
      int cid = j * 256 + tid;
      int row = cid >> 2, cc = cid & 3;
      int cs = cc ^ (row & 3);
      gload_lds16(A0 + (size_t)row * ND + k0 + cs * 8, (char*)lAx + cid * 16);
      gload_lds16(B0 + (size_t)row * ND + k0 + cs * 8, (char*)lBx + cid * 16);
    }
    __syncthreads();
    bf16x8 af[4], bfr[4];
#pragma unroll
    for (int i = 0; i < 4; ++i) {
      int row = m_off + i * 16 + (lane & 15);
      int ch = (lane >> 4) ^ (row & 3);
      af[i] = *(const bf16x8*)((const char*)lAx + row * 64 + ch * 16);
      int rowb = n_off + i * 16 + (lane & 15);
      int chb = (lane >> 4) ^ (rowb & 3);
      bfr[i] = *(const bf16x8*)((const char*)lBx + rowb * 64 + chb * 16);
    }
#pragma unroll
    for (int i = 0; i < 4; ++i)
#pragma unroll
      for (int j2 = 0; j2 < 4; ++j2)
        acc[i][j2] = __builtin_amdgcn_mfma_f32_16x16x32_bf16(af[i], bfr[j2], acc[i][j2], 0, 0, 0);
    __syncthreads();
  }
#pragma unroll
  for (int i = 0; i < 4; ++i)
#pragma unroll
    for (int j2 = 0; j2 < 4; ++j2)
#pragma unroll
      for (int r = 0; r < 4; ++r) {
        int m = m_off + i * 16 + ((lane >> 4) << 2) + r;
        int n = nb * 128 + n_off + j2 * 16 + (lane & 15);
        XP[((size_t)(m * NB + b)) * NG + n] = f2bf(acc[i][j2][r]);
      }
}

// ---------------- fused dispatch (R12 skeleton + K-split MFMA) ----------------
// bids 0..127: LSTM (g_b 0..3 x g_d 0..31). bids 128..255: GEMM for chunk+1.
// 96KB dynamic LDS -> 1 WG/CU. LSTM MFMA: wave (cp,kh)=(wv&3,wv>>2) computes
// col-tiles {2cp,2cp+1} over K-half kh (16 af reads feed 32 MFMAs -> LDS
// read traffic halves); partner waves (wv^4) exchange f32x4 partials via an
// 8KB LDS buffer and each finalizes tile Tf=2cp+kh (substitutes old wv role).
__global__ __launch_bounds__(512, 2) void k_fused(
    const uint16_t* __restrict__ embb,   // [64][1024][1024] bf16
    const uint16_t* __restrict__ Wx,
    const uint16_t* __restrict__ Wh,
    uint16_t* __restrict__ xpA, uint16_t* __restrict__ xpB,
    const float* __restrict__ b_i, const float* __restrict__ b_f,
    const float* __restrict__ b_g, const float* __restrict__ b_o,
    uint16_t* __restrict__ hring,        // [RING][NB][ND] bf16 ring (t mod 32)
    float* __restrict__ cbuf,
    uint32_t* __restrict__ flags,        // [NS][4][32] slots, 16B stride
    float* __restrict__ out, int chunk) {
  extern __shared__ char smem[];
  const int bid = blockIdx.x;
  const int tid = threadIdx.x;

  if (chunk < 0 || bid >= 128) {
    // ---------------- GEMM role: x_proj for chunk+1 ----------------
    const int gc = (chunk < 0) ? 0 : chunk + 1;
    if (gc >= NCHUNK) return;
    uint16_t* XP = (gc & 1) ? xpB : xpA;
    const int nw = (chunk < 0) ? 512 : 256;
    const int widx = ((chunk < 0) ? bid : bid - 128) * 2 + (tid >> 8);
    const int t256 = tid & 255;
    char* lmem = smem + ((tid >> 8) << 14);
    const int t0g = gc * CHUNK;
    for (int job = widx; job < 64 * 32; job += nw) {
      int b = job & 63, nb = job >> 6;
      gemm_tile(embb + ((size_t)b * NS + t0g) * ND, Wx, XP, b, nb, t256, lmem);
    }
    return;
  }

  // ---------------- LSTM role ----------------
  uint16_t* lH = (uint16_t*)smem;                 // 32 KB: 16 rows x 2048 B
  int* lds_sync = (int*)(smem + 32768);
  float* shr = (float*)(smem + 32832);            // 8 KB partial-sum exchange
  const int t0 = chunk * CHUNK;
  const uint16_t* XP = (chunk & 1) ? xpB : xpA;

  const int lane = tid & 63, wv = tid >> 6;
  const int xcd = bid & 7;
  const int g_b = xcd >> 1;
  const int g_d = (xcd & 1) + ((bid >> 3) << 1);  // 0..31

  const int q = lane >> 4, nl = lane & 15;
  const int g = nl & 3;                        // gate id (0=i,1=f,2=g,3=o)
  const int cp = wv & 3;                       // col-pair index
  const int kh = wv >> 2;                      // K-half (0: k<512, 1: k>=512)
  const int Tf = (cp << 1) | kh;               // finalized col-tile 0..7
  const int d_loc = Tf * 4 + (nl >> 2);        // 0..31
  const int dg = g_d * 32 + d_loc;             // finalized global d
  const int dg0 = g_d * 32 + (cp << 3) + (nl >> 2);   // tile 2cp
  const int dg1 = dg0 + 4;                             // tile 2cp+1
  const int bg0 = g_b * 16 + q * 4;            // batch base for r=0..3

  // Wh fragments for BOTH tiles, K-half kh only (128 VGPRs total, as before)
  bf16x8 wfr0[16], wfr1[16];
  {
    const uint16_t* w0 = Wh + ((size_t)g * ND + dg0) * ND + kh * 512;
    const uint16_t* w1 = Wh + ((size_t)g * ND + dg1) * ND + kh * 512;
#pragma unroll
    for (int kk = 0; kk < 16; ++kk) {
      wfr0[kk] = *(const bf16x8*)(w0 + kk * 32 + q * 8);
      wfr1[kk] = *(const bf16x8*)(w1 + kk * 32 + q * 8);
    }
  }

  const float* bptr = (g == 0) ? b_i : (g == 1) ? b_f : (g == 2) ? b_g : b_o;
  const float Bv = bptr[dg];

  float c0, c1, c2s, c3;
  if (t0 == 0) {
    c0 = c1 = c2s = c3 = 0.f;
  } else {
    c0  = cbuf[(size_t)(bg0 + 0) * ND + dg];
    c1  = cbuf[(size_t)(bg0 + 1) * ND + dg];
    c2s = cbuf[(size_t)(bg0 + 2) * ND + dg];
    c3  = cbuf[(size_t)(bg0 + 3) * ND + dg];
  }

  if (tid == 0)
    __hip_atomic_store(lds_sync, t0, __ATOMIC_RELAXED, __HIP_MEMORY_SCOPE_WORKGROUP);
  __syncthreads();

  // preload XP for t0
  const uint16_t* xp0 = XP + ((size_t)bg0) * NG + ((size_t)g << 10) + dg;
  uint16_t xc0 = xp0[0], xc1 = xp0[NG], xc2 = xp0[2 * (size_t)NG], xc3 = xp0[3 * (size_t)NG];

#pragma unroll 1
  for (int t = t0; t < t0 + CHUNK; ++t) {
    f32x4 a0 = {0,0,0,0}, a1 = {0,0,0,0}, e0 = {0,0,0,0}, e1 = {0,0,0,0};
    if (t > 0) {
      if (wv == 0) {
        // gather all 32 producer flags in one 32-lane load (slots 16B-strided)
        const uint32_t* fl = flags + ((((size_t)(t - 1) * 4 + g_b) << 5) + (lane & 31)) * 4;
        uint32_t v;
        do {
          v = __hip_atomic_load(fl, __ATOMIC_RELAXED, __HIP_MEMORY_SCOPE_AGENT);
        } while (__any(v == 0));
        if (lane == 0)
          __hip_atomic_store(lds_sync, t, __ATOMIC_RELAXED, __HIP_MEMORY_SCOPE_WORKGROUP);
      } else {
        while (__hip_atomic_load(lds_sync, __ATOMIC_RELAXED, __HIP_MEMORY_SCOPE_WORKGROUP) < t) {}
      }
      // stage h(t-1) from ring slot (t-1)&31: 32 KB, L1/L2-bypass gload_lds
      const uint16_t* hbase = hring + (size_t)((t - 1) & (RING - 1)) * NB * ND;
#pragma unroll
      for (int j = 0; j < 4; ++j) {
        int ch = wv * 64 + j * 512 + lane;       // 0..2047
        int row = ch >> 7, c = ch & 127;
        const uint16_t* src = hbase + (size_t)(g_b * 16 + row) * ND + ((c ^ (row & 7)) << 3);
        gload_lds16_nc(src, (char*)lH + ch * 16);
      }
      __syncthreads();
    }

    // prefetch next step's XP into regs (covered by MFMA+VALU below)
    int tn = t + 1 < t0 + CHUNK ? t + 1 : t;
    const uint16_t* xpn = XP + (((size_t)(tn - t0) * NB) + bg0) * NG + ((size_t)g << 10) + dg;
    uint16_t xn0 = xpn[0], xn1 = xpn[NG], xn2 = xpn[2 * (size_t)NG], xn3 = xpn[3 * (size_t)NG];

    if (t > 0) {
      // 16 af reads, each feeding 2 MFMAs (tile 2cp and 2cp+1), K-half kh
#pragma unroll
      for (int kk = 0; kk < 16; ++kk) {
        int kg = (kh << 4) + kk;
        int cs = (kg * 4 + q) ^ (nl & 7);
        bf16x8 af = *(const bf16x8*)((const char*)lH + nl * 2048 + cs * 16);
        if (kk & 1) {
          a1 = __builtin_amdgcn_mfma_f32_16x16x32_bf16(af, wfr0[kk], a1, 0, 0, 0);
          e1 = __builtin_amdgcn_mfma_f32_16x16x32_bf16(af, wfr1[kk], e1, 0, 0, 0);
        } else {
          a0 = __builtin_amdgcn_mfma_f32_16x16x32_bf16(af, wfr0[kk], a0, 0, 0, 0);
          e0 = __builtin_amdgcn_mfma_f32_16x16x32_bf16(af, wfr1[kk], e0, 0, 0, 0);
        }
      }
    }

    // K-half reduction across partner waves (wv ^ 4); finalize tile Tf
    f32x4 p0 = a0 + a1;            // partial for tile 2cp   (this K-half)
    f32x4 p1 = e0 + e1;            // partial for tile 2cp+1 (this K-half)
    f32x4 pk = kh ? p1 : p0;       // tile this wave finalizes
    f32x4 ps = kh ? p0 : p1;       // tile the partner finalizes
    *(f32x4*)(shr + ((wv ^ 4) << 8) + (lane << 2)) = ps;
    __syncthreads();
    pk += *(const f32x4*)(shr + (wv << 8) + (lane << 2));

    float xr[4] = { bf2f(xc0), bf2f(xc1), bf2f(xc2), bf2f(xc3) };
    float cc[4] = { c0, c1, c2s, c3 };
    float hval = 0.f;
#pragma unroll
    for (int r = 0; r < 4; ++r) {
      float v = pk[r] + xr[r] + Bv;
      float act = (g == 2) ? tanhf_(v) : sigmoidf_(v);
      float s1 = __shfl_xor(act, 1);
      float pe = (g & 1) ? s1 : act;
      float po = (g & 1) ? act : s1;
      float qe = __shfl_xor(pe, 2);
      float qo = __shfl_xor(po, 2);
      float gi = (g & 2) ? qe : pe;
      float gf = (g & 2) ? qo : po;
      float gg2 = (g & 2) ? pe : qe;
      float go = (g & 2) ? po : qo;
      float cn = __builtin_fmaf(gf, cc[r], gi * gg2);
      cc[r] = cn;
      float h = go * tanhf_(cn);
      if (r == g) hval = h;
    }
    c0 = cc[0]; c1 = cc[1]; c2s = cc[2]; c3 = cc[3];

    // per-wave shuffle-pack: 4 lanes (same q, d_off 0..3) -> u64 in nl<4
    {
      int hv = (int)f2bf(hval);
      int p = __shfl_xor(hv, 4);
      uint32_t v32 = ((nl >> 2) & 1) ? ((uint32_t)p | ((uint32_t)hv << 16))
                                     : ((uint32_t)hv | ((uint32_t)p << 16));
      uint32_t hi = (uint32_t)__shfl_xor((int)v32, 8);
      if (nl < 4) {
        uint64_t val = (uint64_t)v32 | ((uint64_t)hi << 32);
        uint16_t* dst = hring + (size_t)(t & (RING - 1)) * NB * ND
                        + (size_t)(g_b * 16 + q * 4 + nl) * ND + g_d * 32 + Tf * 4;
        __hip_atomic_store((uint64_t*)dst, val, __ATOMIC_RELAXED, __HIP_MEMORY_SCOPE_AGENT);
      }
    }
    if (t == NS - 1) out[(size_t)(bg0 + g) * ND + dg] = hval;

    __syncthreads();   // drains all waves' h stores; guards lH + shr reuse
    if (tid == 0)
      __hip_atomic_store(flags + ((((size_t)t * 4 + g_b) << 5) + g_d) * 4, 1u,
                         __ATOMIC_RELAXED, __HIP_MEMORY_SCOPE_AGENT);

    xc0 = xn0; xc1 = xn1; xc2 = xn2; xc3 = xn3;
  }

  cbuf[(size_t)(bg0 + 0) * ND + dg] = c0;
  if (g == 1) cbuf[(size_t)(bg0 + 1) * ND + dg] = c1;
  if (g == 2) cbuf[(size_t)(bg0 + 2) * ND + dg] = c2s;
  if (g == 3) cbuf[(size_t)(bg0 + 3) * ND + dg] = c3;
  // note: lane with g==0 wrote c0 above; lanes g==1..3 overwrite their rows.
  // (4 lanes share each (bg0+r, dg) only via distinct g -> distinct dg? No:
  //  dg identical across g. Keep original exact semantics instead:)
  {
    float cstore = (g == 0) ? c0 : (g == 1) ? c1 : (g == 2) ? c2s : c3;
    cbuf[(size_t)(bg0 + g) * ND + dg] = cstore;
  }
}

// ---------------- launch ----------------
extern "C" void kernel_launch(void* const* d_in, const int* in_sizes, int n_in,
                              void* d_out, int out_size, void* d_ws, size_t ws_size,
                              hipStream_t stream) {
  const float* emb = (const float*)d_in[0];
  const float* W_ii = (const float*)d_in[1];
  const float* b_ii = (const float*)d_in[2];
  const float* W_if = (const float*)d_in[3];
  const float* b_if = (const float*)d_in[4];
  const float* W_ig = (const float*)d_in[5];
  const float* b_ig = (const float*)d_in[6];
  const float* W_io = (const float*)d_in[7];
  const float* b_io = (const float*)d_in[8];
  const float* W_hi = (const float*)d_in[9];
  const float* W_hf = (const float*)d_in[10];
  const float* W_hg = (const float*)d_in[11];
  const float* W_ho = (const float*)d_in[12];

  char* ws = (char*)d_ws;
  uint16_t* embb  = (uint16_t*)ws;                       // 134217728 B [B][S][D] bf16
  uint16_t* wx    = (uint16_t*)(ws + 134217728);         // 8388608 B
  uint16_t* wh    = (uint16_t*)(ws + 142606336);         // 8388608 B
  uint16_t* xpA   = (uint16_t*)(ws + 150994944);         // 67108864 B
  uint16_t* xpB   = (uint16_t*)(ws + 218103808);         // 67108864 B
  uint16_t* hring = (uint16_t*)(ws + 285212672);         // 4194304 B [RING][NB][ND]
  float*    cbuf  = (float*)(ws + 289406976);            // 262144 B
  uint32_t* flags = (uint32_t*)(ws + 289669120);         // 2097152 B [NS][4][32] x16B

  hipMemsetAsync(flags, 0, 2097152, stream);

  k_cvt<<<2048, 256, 0, stream>>>(emb, embb, 64 * 1024 * 1024 / 4);
  k_cvt8<<<2048, 256, 0, stream>>>(W_ii, W_if, W_ig, W_io, W_hi, W_hf, W_hg, W_ho, wx, wh);

  const int SHM = 98304;   // 96 KB -> 1 WG/CU (R9/R12-verified)
  hipFuncSetAttribute((const void*)k_fused, hipFuncAttributeMaxDynamicSharedMemorySize, SHM);

  // prologue: all 256 WGs compute x_proj for chunk 0
  k_fused<<<256, 512, SHM, stream>>>(embb, wx, wh, xpA, xpB, b_ii, b_if, b_ig, b_io,
                                     hring, cbuf, flags, (float*)d_out, -1);
  for (int chk = 0; chk < NCHUNK; ++chk)
    k_fused<<<256, 512, SHM, stream>>>(embb, wx, wh, xpA, xpB, b_ii, b_if, b_ig, b_io,
                                       hring, cbuf, flags, (float*)d_out, chk);
}

// Round 18
// 3296.004 us; speedup vs baseline: 3.0006x; 1.0356x over previous
//
#include <hip/hip_runtime.h>
#include <stdint.h>

#define NB 64
#define NS 1024
#define ND 1024
#define NG 4096
#define CHUNK 128
#define NCHUNK 8
#define RING 32

typedef __attribute__((ext_vector_type(4))) float f32x4;
typedef __attribute__((ext_vector_type(8))) short bf16x8;

__device__ __forceinline__ float bf2f(uint16_t u) {
  return __uint_as_float(((uint32_t)u) << 16);
}
__device__ __forceinline__ uint16_t f2bf(float f) {
  uint32_t x = __float_as_uint(f);
  return (uint16_t)((x + 0x7fffu + ((x >> 16) & 1u)) >> 16);
}
__device__ __forceinline__ float sigmoidf_(float x) {
  return 1.f / (1.f + __expf(-x));
}
__device__ __forceinline__ float tanhf_(float x) {
  return 1.f - 2.f / (__expf(x + x) + 1.f);
}
__device__ __forceinline__ void gload_lds16(const void* g, void* l) {
  __builtin_amdgcn_global_load_lds(
      (const __attribute__((address_space(1))) uint32_t*)g,
      (__attribute__((address_space(3))) uint32_t*)l, 16, 0, 0);
}
// L1+L2-bypassing variant (cpol SC0|SC1): reads served from L3, where the
// producers' agent-scope stores are visible before their flag.
__device__ __forceinline__ void gload_lds16_nc(const void* g, void* l) {
  __builtin_amdgcn_global_load_lds(
      (const __attribute__((address_space(1))) uint32_t*)g,
      (__attribute__((address_space(3))) uint32_t*)l, 16, 0, 17);
}

// ---------------- convert fp32 -> bf16 (emb) ----------------
__global__ void k_cvt(const float* __restrict__ src, uint16_t* __restrict__ dst, int n4) {
  int stride = gridDim.x * blockDim.x;
  for (int i = blockIdx.x * blockDim.x + threadIdx.x; i < n4; i += stride) {
    float4 v = ((const float4*)src)[i];
    ushort4 o;
    o.x = f2bf(v.x); o.y = f2bf(v.y); o.z = f2bf(v.z); o.w = f2bf(v.w);
    ((ushort4*)dst)[i] = o;
  }
}

// all 8 weight matrices in one launch (saves 7 launch overheads)
__global__ void k_cvt8(const float* w0, const float* w1, const float* w2, const float* w3,
                       const float* w4, const float* w5, const float* w6, const float* w7,
                       uint16_t* wx, uint16_t* wh) {
  int which = blockIdx.x >> 8;
  const float* src;
  uint16_t* dst;
  if      (which == 0) { src = w0; dst = wx; }
  else if (which == 1) { src = w1; dst = wx + 1048576; }
  else if (which == 2) { src = w2; dst = wx + 2097152; }
  else if (which == 3) { src = w3; dst = wx + 3145728; }
  else if (which == 4) { src = w4; dst = wh; }
  else if (which == 5) { src = w5; dst = wh + 1048576; }
  else if (which == 6) { src = w6; dst = wh + 2097152; }
  else                 { src = w7; dst = wh + 3145728; }
  for (int i = (blockIdx.x & 255) * 256 + threadIdx.x; i < 262144; i += 65536) {
    float4 v = ((const float4*)src)[i];
    ushort4 o;
    o.x = f2bf(v.x); o.y = f2bf(v.y); o.z = f2bf(v.z); o.w = f2bf(v.w);
    ((ushort4*)dst)[i] = o;
  }
}

// ---------------- GEMM tile: [128 steps x 1024] x [1024 x 128] -> XP ----------------
__device__ __forceinline__ void gemm_tile(const uint16_t* __restrict__ A0,
                                          const uint16_t* __restrict__ Wx,
                                          uint16_t* __restrict__ XP,
                                          int b, int nb, int tid, char* lmem) {
  uint16_t* lAx = (uint16_t*)lmem;
  uint16_t* lBx = (uint16_t*)(lmem + 8192);
  const uint16_t* B0 = Wx + (size_t)(nb * 128) * ND;
  const int lane = tid & 63, wv = tid >> 6;
  const int m_off = (wv >> 1) << 6, n_off = (wv & 1) << 6;

  f32x4 acc[4][4] = {};
  for (int kb = 0; kb < ND / 32; ++kb) {
    const int k0 = kb * 32;
#pragma unroll
    for (int j = 0; j < 2; ++j) {
      int cid = j * 256 + tid;
      int row = cid >> 2, cc = cid & 3;
      int cs = cc ^ (row & 3);
      gload_lds16(A0 + (size_t)row * ND + k0 + cs * 8, (char*)lAx + cid * 16);
      gload_lds16(B0 + (size_t)row * ND + k0 + cs * 8, (char*)lBx + cid * 16);
    }
    __syncthreads();
    bf16x8 af[4], bfr[4];
#pragma unroll
    for (int i = 0; i < 4; ++i) {
      int row = m_off + i * 16 + (lane & 15);
      int ch = (lane >> 4) ^ (row & 3);
      af[i] = *(const bf16x8*)((const char*)lAx + row * 64 + ch * 16);
      int rowb = n_off + i * 16 + (lane & 15);
      int chb = (lane >> 4) ^ (rowb & 3);
      bfr[i] = *(const bf16x8*)((const char*)lBx + rowb * 64 + chb * 16);
    }
#pragma unroll
    for (int i = 0; i < 4; ++i)
#pragma unroll
      for (int j2 = 0; j2 < 4; ++j2)
        acc[i][j2] = __builtin_amdgcn_mfma_f32_16x16x32_bf16(af[i], bfr[j2], acc[i][j2], 0, 0, 0);
    __syncthreads();
  }
#pragma unroll
  for (int i = 0; i < 4; ++i)
#pragma unroll
    for (int j2 = 0; j2 < 4; ++j2)
#pragma unroll
      for (int r = 0; r < 4; ++r) {
        int m = m_off + i * 16 + ((lane >> 4) << 2) + r;
        int n = nb * 128 + n_off + j2 * 16 + (lane & 15);
        XP[((size_t)(m * NB + b)) * NG + n] = f2bf(acc[i][j2][r]);
      }
}

// ---------------- fused dispatch (R16-verified skeleton + tanh trim) ----------
// bids 0..127: LSTM (g_b 0..3 x g_d 0..31). bids 128..255: GEMM for chunk+1.
// 96KB dynamic LDS -> 1 WG/CU. K-split MFMA: wave (cp,kh)=(wv&3,wv>>2)
// computes col-tiles {2cp,2cp+1} over K-half kh (16 af reads feed 32 MFMAs);
// partner waves (wv^4) exchange f32x4 partials via an 8KB LDS buffer and
// each finalizes tile Tf=2cp+kh.
__global__ __launch_bounds__(512, 2) void k_fused(
    const uint16_t* __restrict__ embb,   // [64][1024][1024] bf16
    const uint16_t* __restrict__ Wx,
    const uint16_t* __restrict__ Wh,
    uint16_t* __restrict__ xpA, uint16_t* __restrict__ xpB,
    const float* __restrict__ b_i, const float* __restrict__ b_f,
    const float* __restrict__ b_g, const float* __restrict__ b_o,
    uint16_t* __restrict__ hring,        // [RING][NB][ND] bf16 ring (t mod 32)
    float* __restrict__ cbuf,
    uint32_t* __restrict__ flags,        // [NS][4][32] slots, 16B stride
    float* __restrict__ out, int chunk) {
  extern __shared__ char smem[];
  const int bid = blockIdx.x;
  const int tid = threadIdx.x;

  if (chunk < 0 || bid >= 128) {
    // ---------------- GEMM role: x_proj for chunk+1 ----------------
    const int gc = (chunk < 0) ? 0 : chunk + 1;
    if (gc >= NCHUNK) return;
    uint16_t* XP = (gc & 1) ? xpB : xpA;
    const int nw = (chunk < 0) ? 512 : 256;
    const int widx = ((chunk < 0) ? bid : bid - 128) * 2 + (tid >> 8);
    const int t256 = tid & 255;
    char* lmem = smem + ((tid >> 8) << 14);
    const int t0g = gc * CHUNK;
    for (int job = widx; job < 64 * 32; job += nw) {
      int b = job & 63, nb = job >> 6;
      gemm_tile(embb + ((size_t)b * NS + t0g) * ND, Wx, XP, b, nb, t256, lmem);
    }
    return;
  }

  // ---------------- LSTM role ----------------
  uint16_t* lH = (uint16_t*)smem;                 // 32 KB: 16 rows x 2048 B
  int* lds_sync = (int*)(smem + 32768);
  float* shr = (float*)(smem + 32832);            // 8 KB partial-sum exchange
  const int t0 = chunk * CHUNK;
  const uint16_t* XP = (chunk & 1) ? xpB : xpA;

  const int lane = tid & 63, wv = tid >> 6;
  const int xcd = bid & 7;
  const int g_b = xcd >> 1;
  const int g_d = (xcd & 1) + ((bid >> 3) << 1);  // 0..31

  const int q = lane >> 4, nl = lane & 15;
  const int g = nl & 3;                        // gate id (0=i,1=f,2=g,3=o)
  const int cp = wv & 3;                       // col-pair index
  const int kh = wv >> 2;                      // K-half (0: k<512, 1: k>=512)
  const int Tf = (cp << 1) | kh;               // finalized col-tile 0..7
  const int d_loc = Tf * 4 + (nl >> 2);        // 0..31
  const int dg = g_d * 32 + d_loc;             // finalized global d
  const int dg0 = g_d * 32 + (cp << 3) + (nl >> 2);   // tile 2cp
  const int dg1 = dg0 + 4;                             // tile 2cp+1
  const int bg0 = g_b * 16 + q * 4;            // batch base for r=0..3

  // Wh fragments for BOTH tiles, K-half kh only (128 VGPRs total)
  bf16x8 wfr0[16], wfr1[16];
  {
    const uint16_t* w0 = Wh + ((size_t)g * ND + dg0) * ND + kh * 512;
    const uint16_t* w1 = Wh + ((size_t)g * ND + dg1) * ND + kh * 512;
#pragma unroll
    for (int kk = 0; kk < 16; ++kk) {
      wfr0[kk] = *(const bf16x8*)(w0 + kk * 32 + q * 8);
      wfr1[kk] = *(const bf16x8*)(w1 + kk * 32 + q * 8);
    }
  }

  const float* bptr = (g == 0) ? b_i : (g == 1) ? b_f : (g == 2) ? b_g : b_o;
  const float Bv = bptr[dg];

  float c0, c1, c2s, c3;
  if (t0 == 0) {
    c0 = c1 = c2s = c3 = 0.f;
  } else {
    c0  = cbuf[(size_t)(bg0 + 0) * ND + dg];
    c1  = cbuf[(size_t)(bg0 + 1) * ND + dg];
    c2s = cbuf[(size_t)(bg0 + 2) * ND + dg];
    c3  = cbuf[(size_t)(bg0 + 3) * ND + dg];
  }

  if (tid == 0)
    __hip_atomic_store(lds_sync, t0, __ATOMIC_RELAXED, __HIP_MEMORY_SCOPE_WORKGROUP);
  __syncthreads();

  // preload XP for t0
  const uint16_t* xp0 = XP + ((size_t)bg0) * NG + ((size_t)g << 10) + dg;
  uint16_t xc0 = xp0[0], xc1 = xp0[NG], xc2 = xp0[2 * (size_t)NG], xc3 = xp0[3 * (size_t)NG];

#pragma unroll 1
  for (int t = t0; t < t0 + CHUNK; ++t) {
    f32x4 a0 = {0,0,0,0}, a1 = {0,0,0,0}, e0 = {0,0,0,0}, e1 = {0,0,0,0};
    if (t > 0) {
      if (wv == 0) {
        // gather all 32 producer flags in one 32-lane load (slots 16B-strided)
        const uint32_t* fl = flags + ((((size_t)(t - 1) * 4 + g_b) << 5) + (lane & 31)) * 4;
        uint32_t v;
        do {
          v = __hip_atomic_load(fl, __ATOMIC_RELAXED, __HIP_MEMORY_SCOPE_AGENT);
        } while (__any(v == 0));
        if (lane == 0)
          __hip_atomic_store(lds_sync, t, __ATOMIC_RELAXED, __HIP_MEMORY_SCOPE_WORKGROUP);
      } else {
        while (__hip_atomic_load(lds_sync, __ATOMIC_RELAXED, __HIP_MEMORY_SCOPE_WORKGROUP) < t) {}
      }
      // stage h(t-1) from ring slot (t-1)&31: 32 KB, L1/L2-bypass gload_lds
      const uint16_t* hbase = hring + (size_t)((t - 1) & (RING - 1)) * NB * ND;
#pragma unroll
      for (int j = 0; j < 4; ++j) {
        int ch = wv * 64 + j * 512 + lane;       // 0..2047
        int row = ch >> 7, c = ch & 127;
        const uint16_t* src = hbase + (size_t)(g_b * 16 + row) * ND + ((c ^ (row & 7)) << 3);
        gload_lds16_nc(src, (char*)lH + ch * 16);
      }
      __syncthreads();
    }

    // prefetch next step's XP into regs (covered by MFMA+VALU below)
    int tn = t + 1 < t0 + CHUNK ? t + 1 : t;
    const uint16_t* xpn = XP + (((size_t)(tn - t0) * NB) + bg0) * NG + ((size_t)g << 10) + dg;
    uint16_t xn0 = xpn[0], xn1 = xpn[NG], xn2 = xpn[2 * (size_t)NG], xn3 = xpn[3 * (size_t)NG];

    if (t > 0) {
      // 16 af reads, each feeding 2 MFMAs (tile 2cp and 2cp+1), K-half kh
#pragma unroll
      for (int kk = 0; kk < 16; ++kk) {
        int kg = (kh << 4) + kk;
        int cs = (kg * 4 + q) ^ (nl & 7);
        bf16x8 af = *(const bf16x8*)((const char*)lH + nl * 2048 + cs * 16);
        if (kk & 1) {
          a1 = __builtin_amdgcn_mfma_f32_16x16x32_bf16(af, wfr0[kk], a1, 0, 0, 0);
          e1 = __builtin_amdgcn_mfma_f32_16x16x32_bf16(af, wfr1[kk], e1, 0, 0, 0);
        } else {
          a0 = __builtin_amdgcn_mfma_f32_16x16x32_bf16(af, wfr0[kk], a0, 0, 0, 0);
          e0 = __builtin_amdgcn_mfma_f32_16x16x32_bf16(af, wfr1[kk], e0, 0, 0, 0);
        }
      }
    }

    // K-half reduction across partner waves (wv ^ 4); finalize tile Tf
    f32x4 p0 = a0 + a1;            // partial for tile 2cp   (this K-half)
    f32x4 p1 = e0 + e1;            // partial for tile 2cp+1 (this K-half)
    f32x4 pk = kh ? p1 : p0;       // tile this wave finalizes
    f32x4 ps = kh ? p0 : p1;       // tile the partner finalizes
    *(f32x4*)(shr + ((wv ^ 4) << 8) + (lane << 2)) = ps;
    __syncthreads();
    pk += *(const f32x4*)(shr + (wv << 8) + (lane << 2));

    float xr[4] = { bf2f(xc0), bf2f(xc1), bf2f(xc2), bf2f(xc3) };
    float cc[4] = { c0, c1, c2s, c3 };
    float cn_sel = 0.f, go_sel = 0.f;
#pragma unroll
    for (int r = 0; r < 4; ++r) {
      float v = pk[r] + xr[r] + Bv;
      float act = (g == 2) ? tanhf_(v) : sigmoidf_(v);
      float s1 = __shfl_xor(act, 1);
      float pe = (g & 1) ? s1 : act;
      float po = (g & 1) ? act : s1;
      float qe = __shfl_xor(pe, 2);
      float qo = __shfl_xor(po, 2);
      float gi = (g & 2) ? qe : pe;
      float gf = (g & 2) ? qo : po;
      float gg2 = (g & 2) ? pe : qe;
      float go = (g & 2) ? po : qo;
      float cn = __builtin_fmaf(gf, cc[r], gi * gg2);
      cc[r] = cn;
      if (r == g) { cn_sel = cn; go_sel = go; }
    }
    float hval = go_sel * tanhf_(cn_sel);   // only the published row needs tanh
    c0 = cc[0]; c1 = cc[1]; c2s = cc[2]; c3 = cc[3];

    // per-wave shuffle-pack: 4 lanes (same q, d_off 0..3) -> u64 in nl<4
    {
      int hv = (int)f2bf(hval);
      int p = __shfl_xor(hv, 4);
      uint32_t v32 = ((nl >> 2) & 1) ? ((uint32_t)p | ((uint32_t)hv << 16))
                                     : ((uint32_t)hv | ((uint32_t)p << 16));
      uint32_t hi = (uint32_t)__shfl_xor((int)v32, 8);
      if (nl < 4) {
        uint64_t val = (uint64_t)v32 | ((uint64_t)hi << 32);
        uint16_t* dst = hring + (size_t)(t & (RING - 1)) * NB * ND
                        + (size_t)(g_b * 16 + q * 4 + nl) * ND + g_d * 32 + Tf * 4;
        __hip_atomic_store((uint64_t*)dst, val, __ATOMIC_RELAXED, __HIP_MEMORY_SCOPE_AGENT);
      }
    }
    if (t == NS - 1) out[(size_t)(bg0 + g) * ND + dg] = hval;

    __syncthreads();   // drains all waves' h stores; guards lH + shr reuse
    if (tid == 0)
      __hip_atomic_store(flags + ((((size_t)t * 4 + g_b) << 5) + g_d) * 4, 1u,
                         __ATOMIC_RELAXED, __HIP_MEMORY_SCOPE_AGENT);

    xc0 = xn0; xc1 = xn1; xc2 = xn2; xc3 = xn3;
  }

  float cstore = (g == 0) ? c0 : (g == 1) ? c1 : (g == 2) ? c2s : c3;
  cbuf[(size_t)(bg0 + g) * ND + dg] = cstore;
}

// ---------------- launch ----------------
extern "C" void kernel_launch(void* const* d_in, const int* in_sizes, int n_in,
                              void* d_out, int out_size, void* d_ws, size_t ws_size,
                              hipStream_t stream) {
  const float* emb = (const float*)d_in[0];
  const float* W_ii = (const float*)d_in[1];
  const float* b_ii = (const float*)d_in[2];
  const float* W_if = (const float*)d_in[3];
  const float* b_if = (const float*)d_in[4];
  const float* W_ig = (const float*)d_in[5];
  const float* b_ig = (const float*)d_in[6];
  const float* W_io = (const float*)d_in[7];
  const float* b_io = (const float*)d_in[8];
  const float* W_hi = (const float*)d_in[9];
  const float* W_hf = (const float*)d_in[10];
  const float* W_hg = (const float*)d_in[11];
  const float* W_ho = (const float*)d_in[12];

  char* ws = (char*)d_ws;
  uint16_t* embb  = (uint16_t*)ws;                       // 134217728 B [B][S][D] bf16
  uint16_t* wx    = (uint16_t*)(ws + 134217728);         // 8388608 B
  uint16_t* wh    = (uint16_t*)(ws + 142606336);         // 8388608 B
  uint16_t* xpA   = (uint16_t*)(ws + 150994944);         // 67108864 B
  uint16_t* xpB   = (uint16_t*)(ws + 218103808);         // 67108864 B
  uint16_t* hring = (uint16_t*)(ws + 285212672);         // 4194304 B [RING][NB][ND]
  float*    cbuf  = (float*)(ws + 289406976);            // 262144 B
  uint32_t* flags = (uint32_t*)(ws + 289669120);         // 2097152 B [NS][4][32] x16B

  hipMemsetAsync(flags, 0, 2097152, stream);

  k_cvt<<<2048, 256, 0, stream>>>(emb, embb, 64 * 1024 * 1024 / 4);
  k_cvt8<<<2048, 256, 0, stream>>>(W_ii, W_if, W_ig, W_io, W_hi, W_hf, W_hg, W_ho, wx, wh);

  const int SHM = 98304;   // 96 KB -> 1 WG/CU (R9/R12-verified)
  hipFuncSetAttribute((const void*)k_fused, hipFuncAttributeMaxDynamicSharedMemorySize, SHM);

  // prologue: all 256 WGs compute x_proj for chunk 0
  k_fused<<<256, 512, SHM, stream>>>(embb, wx, wh, xpA, xpB, b_ii, b_if, b_ig, b_io,
                                     hring, cbuf, flags, (float*)d_out, -1);
  for (int chk = 0; chk < NCHUNK; ++chk)
    k_fused<<<256, 512, SHM, stream>>>(embb, wx, wh, xpA, xpB, b_ii, b_if, b_ig, b_io,
                                       hring, cbuf, flags, (float*)d_out, chk);
}

// Round 19
// 3206.848 us; speedup vs baseline: 3.0841x; 1.0278x over previous
//
#include <hip/hip_runtime.h>
#include <stdint.h>

#define NB 64
#define NS 1024
#define ND 1024
#define NG 4096
#define CHUNK 128
#define NCHUNK 8
#define RING 32

typedef __attribute__((ext_vector_type(4))) float f32x4;
typedef __attribute__((ext_vector_type(8))) short bf16x8;

__device__ __forceinline__ float bf2f(uint16_t u) {
  return __uint_as_float(((uint32_t)u) << 16);
}
__device__ __forceinline__ uint16_t f2bf(float f) {
  uint32_t x = __float_as_uint(f);
  return (uint16_t)((x + 0x7fffu + ((x >> 16) & 1u)) >> 16);
}
__device__ __forceinline__ float sigmoidf_(float x) {
  return 1.f / (1.f + __expf(-x));
}
__device__ __forceinline__ float tanhf_(float x) {
  return 1.f - 2.f / (__expf(x + x) + 1.f);
}
__device__ __forceinline__ void gload_lds16(const void* g, void* l) {
  __builtin_amdgcn_global_load_lds(
      (const __attribute__((address_space(1))) uint32_t*)g,
      (__attribute__((address_space(3))) uint32_t*)l, 16, 0, 0);
}
// L1+L2-bypassing variant (cpol SC0|SC1): reads served from L3, where the
// producers' agent-scope stores are visible before their flag.
__device__ __forceinline__ void gload_lds16_nc(const void* g, void* l) {
  __builtin_amdgcn_global_load_lds(
      (const __attribute__((address_space(1))) uint32_t*)g,
      (__attribute__((address_space(3))) uint32_t*)l, 16, 0, 17);
}

// ---------------- convert fp32 -> bf16 (emb) ----------------
__global__ void k_cvt(const float* __restrict__ src, uint16_t* __restrict__ dst, int n4) {
  int stride = gridDim.x * blockDim.x;
  for (int i = blockIdx.x * blockDim.x + threadIdx.x; i < n4; i += stride) {
    float4 v = ((const float4*)src)[i];
    ushort4 o;
    o.x = f2bf(v.x); o.y = f2bf(v.y); o.z = f2bf(v.z); o.w = f2bf(v.w);
    ((ushort4*)dst)[i] = o;
  }
}

// all 8 weight matrices in one launch (saves 7 launch overheads)
__global__ void k_cvt8(const float* w0, const float* w1, const float* w2, const float* w3,
                       const float* w4, const float* w5, const float* w6, const float* w7,
                       uint16_t* wx, uint16_t* wh) {
  int which = blockIdx.x >> 8;
  const float* src;
  uint16_t* dst;
  if      (which == 0) { src = w0; dst = wx; }
  else if (which == 1) { src = w1; dst = wx + 1048576; }
  else if (which == 2) { src = w2; dst = wx + 2097152; }
  else if (which == 3) { src = w3; dst = wx + 3145728; }
  else if (which == 4) { src = w4; dst = wh; }
  else if (which == 5) { src = w5; dst = wh + 1048576; }
  else if (which == 6) { src = w6; dst = wh + 2097152; }
  else                 { src = w7; dst = wh + 3145728; }
  for (int i = (blockIdx.x & 255) * 256 + threadIdx.x; i < 262144; i += 65536) {
    float4 v = ((const float4*)src)[i];
    ushort4 o;
    o.x = f2bf(v.x); o.y = f2bf(v.y); o.z = f2bf(v.z); o.w = f2bf(v.w);
    ((ushort4*)dst)[i] = o;
  }
}

// ---------------- GEMM tile: [128 steps x 1024] x [1024 x 128] -> XP ----------------
__device__ __forceinline__ void gemm_tile(const uint16_t* __restrict__ A0,
                                          const uint16_t* __restrict__ Wx,
                                          uint16_t* __restrict__ XP,
                                          int b, int nb, int tid, char* lmem) {
  uint16_t* lAx = (uint16_t*)lmem;
  uint16_t* lBx = (uint16_t*)(lmem + 8192);
  const uint16_t* B0 = Wx + (size_t)(nb * 128) * ND;
  const int lane = tid & 63, wv = tid >> 6;
  const int m_off = (wv >> 1) << 6, n_off = (wv & 1) << 6;

  f32x4 acc[4][4] = {};
  for (int kb = 0; kb < ND / 32; ++kb) {
    const int k0 = kb * 32;
#pragma unroll
    for (int j = 0; j < 2; ++j) {
      int cid = j * 256 + tid;
      int row = cid >> 2, cc = cid & 3;
      int cs = cc ^ (row & 3);
      gload_lds16(A0 + (size_t)row * ND + k0 + cs * 8, (char*)lAx + cid * 16);
      gload_lds16(B0 + (size_t)row * ND + k0 + cs * 8, (char*)lBx + cid * 16);
    }
    __syncthreads();
    bf16x8 af[4], bfr[4];
#pragma unroll
    for (int i = 0; i < 4; ++i) {
      int row = m_off + i * 16 + (lane & 15);
      int ch = (lane >> 4) ^ (row & 3);
      af[i] = *(const bf16x8*)((const char*)lAx + row * 64 + ch * 16);
      int rowb = n_off + i * 16 + (lane & 15);
      int chb = (lane >> 4) ^ (rowb & 3);
      bfr[i] = *(const bf16x8*)((const char*)lBx + rowb * 64 + chb * 16);
    }
#pragma unroll
    for (int i = 0; i < 4; ++i)
#pragma unroll
      for (int j2 = 0; j2 < 4; ++j2)
        acc[i][j2] = __builtin_amdgcn_mfma_f32_16x16x32_bf16(af[i], bfr[j2], acc[i][j2], 0, 0, 0);
    __syncthreads();
  }
#pragma unroll
  for (int i = 0; i < 4; ++i)
#pragma unroll
    for (int j2 = 0; j2 < 4; ++j2)
#pragma unroll
      for (int r = 0; r < 4; ++r) {
        int m = m_off + i * 16 + ((lane >> 4) << 2) + r;
        int n = nb * 128 + n_off + j2 * 16 + (lane & 15);
        XP[((size_t)(m * NB + b)) * NG + n] = f2bf(acc[i][j2][r]);
      }
}

// ---------------- fused dispatch (R18 + all-wave poll + hoisted XP prefetch) ----
// bids 0..127: LSTM (g_b 0..3 x g_d 0..31). bids 128..255: GEMM for chunk+1.
// 96KB dynamic LDS -> 1 WG/CU. K-split MFMA: wave (cp,kh)=(wv&3,wv>>2)
// computes col-tiles {2cp,2cp+1} over K-half kh; partner waves (wv^4)
// exchange f32x4 partials via LDS and each finalizes tile Tf=2cp+kh.
// All 8 waves poll the 32 producer flags directly (no LDS release hop).
__global__ __launch_bounds__(512, 2) void k_fused(
    const uint16_t* __restrict__ embb,   // [64][1024][1024] bf16
    const uint16_t* __restrict__ Wx,
    const uint16_t* __restrict__ Wh,
    uint16_t* __restrict__ xpA, uint16_t* __restrict__ xpB,
    const float* __restrict__ b_i, const float* __restrict__ b_f,
    const float* __restrict__ b_g, const float* __restrict__ b_o,
    uint16_t* __restrict__ hring,        // [RING][NB][ND] bf16 ring (t mod 32)
    float* __restrict__ cbuf,
    uint32_t* __restrict__ flags,        // [NS][4][32] slots, 16B stride
    float* __restrict__ out, int chunk) {
  extern __shared__ char smem[];
  const int bid = blockIdx.x;
  const int tid = threadIdx.x;

  if (chunk < 0 || bid >= 128) {
    // ---------------- GEMM role: x_proj for chunk+1 ----------------
    const int gc = (chunk < 0) ? 0 : chunk + 1;
    if (gc >= NCHUNK) return;
    uint16_t* XP = (gc & 1) ? xpB : xpA;
    const int nw = (chunk < 0) ? 512 : 256;
    const int widx = ((chunk < 0) ? bid : bid - 128) * 2 + (tid >> 8);
    const int t256 = tid & 255;
    char* lmem = smem + ((tid >> 8) << 14);
    const int t0g = gc * CHUNK;
    for (int job = widx; job < 64 * 32; job += nw) {
      int b = job & 63, nb = job >> 6;
      gemm_tile(embb + ((size_t)b * NS + t0g) * ND, Wx, XP, b, nb, t256, lmem);
    }
    return;
  }

  // ---------------- LSTM role ----------------
  uint16_t* lH = (uint16_t*)smem;                 // 32 KB: 16 rows x 2048 B
  float* shr = (float*)(smem + 32832);            // 8 KB partial-sum exchange
  const int t0 = chunk * CHUNK;
  const uint16_t* XP = (chunk & 1) ? xpB : xpA;

  const int lane = tid & 63, wv = tid >> 6;
  const int xcd = bid & 7;
  const int g_b = xcd >> 1;
  const int g_d = (xcd & 1) + ((bid >> 3) << 1);  // 0..31

  const int q = lane >> 4, nl = lane & 15;
  const int g = nl & 3;                        // gate id (0=i,1=f,2=g,3=o)
  const int cp = wv & 3;                       // col-pair index
  const int kh = wv >> 2;                      // K-half (0: k<512, 1: k>=512)
  const int Tf = (cp << 1) | kh;               // finalized col-tile 0..7
  const int d_loc = Tf * 4 + (nl >> 2);        // 0..31
  const int dg = g_d * 32 + d_loc;             // finalized global d
  const int dg0 = g_d * 32 + (cp << 3) + (nl >> 2);   // tile 2cp
  const int dg1 = dg0 + 4;                             // tile 2cp+1
  const int bg0 = g_b * 16 + q * 4;            // batch base for r=0..3

  // Wh fragments for BOTH tiles, K-half kh only (128 VGPRs total)
  bf16x8 wfr0[16], wfr1[16];
  {
    const uint16_t* w0 = Wh + ((size_t)g * ND + dg0) * ND + kh * 512;
    const uint16_t* w1 = Wh + ((size_t)g * ND + dg1) * ND + kh * 512;
#pragma unroll
    for (int kk = 0; kk < 16; ++kk) {
      wfr0[kk] = *(const bf16x8*)(w0 + kk * 32 + q * 8);
      wfr1[kk] = *(const bf16x8*)(w1 + kk * 32 + q * 8);
    }
  }

  const float* bptr = (g == 0) ? b_i : (g == 1) ? b_f : (g == 2) ? b_g : b_o;
  const float Bv = bptr[dg];

  float c0, c1, c2s, c3;
  if (t0 == 0) {
    c0 = c1 = c2s = c3 = 0.f;
  } else {
    c0  = cbuf[(size_t)(bg0 + 0) * ND + dg];
    c1  = cbuf[(size_t)(bg0 + 1) * ND + dg];
    c2s = cbuf[(size_t)(bg0 + 2) * ND + dg];
    c3  = cbuf[(size_t)(bg0 + 3) * ND + dg];
  }
  __syncthreads();

  // preload XP for t0
  const uint16_t* xp0 = XP + ((size_t)bg0) * NG + ((size_t)g << 10) + dg;
  uint16_t xc0 = xp0[0], xc1 = xp0[NG], xc2 = xp0[2 * (size_t)NG], xc3 = xp0[3 * (size_t)NG];

#pragma unroll 1
  for (int t = t0; t < t0 + CHUNK; ++t) {
    // prefetch next step's XP FIRST (independent of flags; latency hides
    // under poll+stage+MFMA)
    int tn = t + 1 < t0 + CHUNK ? t + 1 : t;
    const uint16_t* xpn = XP + (((size_t)(tn - t0) * NB) + bg0) * NG + ((size_t)g << 10) + dg;
    uint16_t xn0 = xpn[0], xn1 = xpn[NG], xn2 = xpn[2 * (size_t)NG], xn3 = xpn[3 * (size_t)NG];

    f32x4 a0 = {0,0,0,0}, a1 = {0,0,0,0}, e0 = {0,0,0,0}, e1 = {0,0,0,0};
    if (t > 0) {
      // all 8 waves poll the 32 producer flags directly (no LDS release hop)
      const uint32_t* fl = flags + ((((size_t)(t - 1) * 4 + g_b) << 5) + (lane & 31)) * 4;
      uint32_t v;
      do {
        v = __hip_atomic_load(fl, __ATOMIC_RELAXED, __HIP_MEMORY_SCOPE_AGENT);
      } while (__any(v == 0));
      // stage h(t-1) from ring slot (t-1)&31: 32 KB, L1/L2-bypass gload_lds
      const uint16_t* hbase = hring + (size_t)((t - 1) & (RING - 1)) * NB * ND;
#pragma unroll
      for (int j = 0; j < 4; ++j) {
        int ch = wv * 64 + j * 512 + lane;       // 0..2047
        int row = ch >> 7, c = ch & 127;
        const uint16_t* src = hbase + (size_t)(g_b * 16 + row) * ND + ((c ^ (row & 7)) << 3);
        gload_lds16_nc(src, (char*)lH + ch * 16);
      }
      __syncthreads();

      // 16 af reads, each feeding 2 MFMAs (tile 2cp and 2cp+1), K-half kh
#pragma unroll
      for (int kk = 0; kk < 16; ++kk) {
        int kg = (kh << 4) + kk;
        int cs = (kg * 4 + q) ^ (nl & 7);
        bf16x8 af = *(const bf16x8*)((const char*)lH + nl * 2048 + cs * 16);
        if (kk & 1) {
          a1 = __builtin_amdgcn_mfma_f32_16x16x32_bf16(af, wfr0[kk], a1, 0, 0, 0);
          e1 = __builtin_amdgcn_mfma_f32_16x16x32_bf16(af, wfr1[kk], e1, 0, 0, 0);
        } else {
          a0 = __builtin_amdgcn_mfma_f32_16x16x32_bf16(af, wfr0[kk], a0, 0, 0, 0);
          e0 = __builtin_amdgcn_mfma_f32_16x16x32_bf16(af, wfr1[kk], e0, 0, 0, 0);
        }
      }
    }

    // K-half reduction across partner waves (wv ^ 4); finalize tile Tf
    f32x4 p0 = a0 + a1;            // partial for tile 2cp   (this K-half)
    f32x4 p1 = e0 + e1;            // partial for tile 2cp+1 (this K-half)
    f32x4 pk = kh ? p1 : p0;       // tile this wave finalizes
    f32x4 ps = kh ? p0 : p1;       // tile the partner finalizes
    *(f32x4*)(shr + ((wv ^ 4) << 8) + (lane << 2)) = ps;
    __syncthreads();
    pk += *(const f32x4*)(shr + (wv << 8) + (lane << 2));

    float xr[4] = { bf2f(xc0), bf2f(xc1), bf2f(xc2), bf2f(xc3) };
    float cc[4] = { c0, c1, c2s, c3 };
    float cn_sel = 0.f, go_sel = 0.f;
#pragma unroll
    for (int r = 0; r < 4; ++r) {
      float v = pk[r] + xr[r] + Bv;
      float act = (g == 2) ? tanhf_(v) : sigmoidf_(v);
      float s1 = __shfl_xor(act, 1);
      float pe = (g & 1) ? s1 : act;
      float po = (g & 1) ? act : s1;
      float qe = __shfl_xor(pe, 2);
      float qo = __shfl_xor(po, 2);
      float gi = (g & 2) ? qe : pe;
      float gf = (g & 2) ? qo : po;
      float gg2 = (g & 2) ? pe : qe;
      float go = (g & 2) ? po : qo;
      float cn = __builtin_fmaf(gf, cc[r], gi * gg2);
      cc[r] = cn;
      if (r == g) { cn_sel = cn; go_sel = go; }
    }
    float hval = go_sel * tanhf_(cn_sel);   // only the published row needs tanh
    c0 = cc[0]; c1 = cc[1]; c2s = cc[2]; c3 = cc[3];

    // per-wave shuffle-pack: 4 lanes (same q, d_off 0..3) -> u64 in nl<4
    {
      int hv = (int)f2bf(hval);
      int p = __shfl_xor(hv, 4);
      uint32_t v32 = ((nl >> 2) & 1) ? ((uint32_t)p | ((uint32_t)hv << 16))
                                     : ((uint32_t)hv | ((uint32_t)p << 16));
      uint32_t hi = (uint32_t)__shfl_xor((int)v32, 8);
      if (nl < 4) {
        uint64_t val = (uint64_t)v32 | ((uint64_t)hi << 32);
        uint16_t* dst = hring + (size_t)(t & (RING - 1)) * NB * ND
                        + (size_t)(g_b * 16 + q * 4 + nl) * ND + g_d * 32 + Tf * 4;
        __hip_atomic_store((uint64_t*)dst, val, __ATOMIC_RELAXED, __HIP_MEMORY_SCOPE_AGENT);
      }
    }
    if (t == NS - 1) out[(size_t)(bg0 + g) * ND + dg] = hval;

    __syncthreads();   // drains all waves' h stores; guards lH + shr reuse
    if (tid == 0)
      __hip_atomic_store(flags + ((((size_t)t * 4 + g_b) << 5) + g_d) * 4, 1u,
                         __ATOMIC_RELAXED, __HIP_MEMORY_SCOPE_AGENT);

    xc0 = xn0; xc1 = xn1; xc2 = xn2; xc3 = xn3;
  }

  float cstore = (g == 0) ? c0 : (g == 1) ? c1 : (g == 2) ? c2s : c3;
  cbuf[(size_t)(bg0 + g) * ND + dg] = cstore;
}

// ---------------- launch ----------------
extern "C" void kernel_launch(void* const* d_in, const int* in_sizes, int n_in,
                              void* d_out, int out_size, void* d_ws, size_t ws_size,
                              hipStream_t stream) {
  const float* emb = (const float*)d_in[0];
  const float* W_ii = (const float*)d_in[1];
  const float* b_ii = (const float*)d_in[2];
  const float* W_if = (const float*)d_in[3];
  const float* b_if = (const float*)d_in[4];
  const float* W_ig = (const float*)d_in[5];
  const float* b_ig = (const float*)d_in[6];
  const float* W_io = (const float*)d_in[7];
  const float* b_io = (const float*)d_in[8];
  const float* W_hi = (const float*)d_in[9];
  const float* W_hf = (const float*)d_in[10];
  const float* W_hg = (const float*)d_in[11];
  const float* W_ho = (const float*)d_in[12];

  char* ws = (char*)d_ws;
  uint16_t* embb  = (uint16_t*)ws;                       // 134217728 B [B][S][D] bf16
  uint16_t* wx    = (uint16_t*)(ws + 134217728);         // 8388608 B
  uint16_t* wh    = (uint16_t*)(ws + 142606336);         // 8388608 B
  uint16_t* xpA   = (uint16_t*)(ws + 150994944);         // 67108864 B
  uint16_t* xpB   = (uint16_t*)(ws + 218103808);         // 67108864 B
  uint16_t* hring = (uint16_t*)(ws + 285212672);         // 4194304 B [RING][NB][ND]
  float*    cbuf  = (float*)(ws + 289406976);            // 262144 B
  uint32_t* flags = (uint32_t*)(ws + 289669120);         // 2097152 B [NS][4][32] x16B

  hipMemsetAsync(flags, 0, 2097152, stream);

  k_cvt<<<2048, 256, 0, stream>>>(emb, embb, 64 * 1024 * 1024 / 4);
  k_cvt8<<<2048, 256, 0, stream>>>(W_ii, W_if, W_ig, W_io, W_hi, W_hf, W_hg, W_ho, wx, wh);

  const int SHM = 98304;   // 96 KB -> 1 WG/CU (R9/R12-verified)
  hipFuncSetAttribute((const void*)k_fused, hipFuncAttributeMaxDynamicSharedMemorySize, SHM);

  // prologue: all 256 WGs compute x_proj for chunk 0
  k_fused<<<256, 512, SHM, stream>>>(embb, wx, wh, xpA, xpB, b_ii, b_if, b_ig, b_io,
                                     hring, cbuf, flags, (float*)d_out, -1);
  for (int chk = 0; chk < NCHUNK; ++chk)
    k_fused<<<256, 512, SHM, stream>>>(embb, wx, wh, xpA, xpB, b_ii, b_if, b_ig, b_io,
                                       hring, cbuf, flags, (float*)d_out, chk);
}